// Round 3
// baseline (363.857 us; speedup 1.0000x reference)
//
#include <hip/hip_runtime.h>
#include <cmath>

#define NB    128      // batches
#define DIM_  640
#define MM    100      // inner dim (K, unpadded)
#define LDK   136      // LDS row stride in halfs (128 + 8 pad)
#define TSF   66       // f32 transpose-tile row stride in dwords (<=2-way bank aliasing)

typedef _Float16 half8 __attribute__((ext_vector_type(8)));
typedef _Float16 half4_t __attribute__((ext_vector_type(4)));
typedef float f32x4 __attribute__((ext_vector_type(4)));

// ---------------------------------------------------------------- prep: d[b,i] = sum_m f16(x)^2 ; zero rowsum/totsum
__global__ __launch_bounds__(256) void prep_d(const float* __restrict__ x,
                                              float* __restrict__ d,
                                              float* __restrict__ rowsum,
                                              float* __restrict__ totsum) {
    if (blockIdx.x < (NB * DIM_) / 256)          // 320 blocks zero the 81920-float rowsum
        rowsum[blockIdx.x * 256 + threadIdx.x] = 0.f;
    if (blockIdx.x == 320 && threadIdx.x < NB)   // one block zeroes totsum
        totsum[threadIdx.x] = 0.f;
    const int row  = blockIdx.x * 4 + (threadIdx.x >> 6);   // 4 waves/block, 1 row/wave
    const int lane = threadIdx.x & 63;
    const float* xr = x + (size_t)row * MM;
    float a = (float)(_Float16)xr[lane];
    float s = a * a;
    if (lane < MM - 64) {
        float c = (float)(_Float16)xr[64 + lane];
        s += c * c;
    }
    #pragma unroll
    for (int off = 32; off; off >>= 1) s += __shfl_down(s, off, 64);
    if (lane == 0) d[row] = s;
}

// ---------------------------------------------------------------- stage 64 rows of x -> f16 LDS (zero-padded K)
__device__ inline void stage_tile(const float* __restrict__ src,
                                  _Float16* lds, int tid) {
    for (int c = tid; c < 64 * 25; c += 256) {
        const int row = c / 25;
        const int pos = c - row * 25;                 // float4 units
        const float4 v = *(const float4*)(src + (size_t)row * MM + pos * 4);
        half4_t h;
        h.x = (_Float16)v.x; h.y = (_Float16)v.y; h.z = (_Float16)v.z; h.w = (_Float16)v.w;
        *(half4_t*)(&lds[row * LDK + pos * 4]) = h;
    }
    for (int i = tid; i < 64 * 28; i += 256) {        // zero pad k = 100..127
        const int row = i / 28;
        const int k = 100 + (i - row * 28);
        lds[row * LDK + k] = (_Float16)0.f;
    }
}

// ---------------------------------------------------------------- fused pass: one block per (batch, tile-pair it<=jt)
// MODE 0: accumulate row sums (and symmetric col sums) + per-batch total
// MODE 1: recompute dcov tile, center with means, write both triangles
template <int MODE>
__global__ __launch_bounds__(256) void bdc_pass(
        const float* __restrict__ x, const float* __restrict__ d,
        const float* __restrict__ t,
        float* __restrict__ rowsum, float* __restrict__ totsum,
        float* __restrict__ out) {
    __shared__ alignas(16) _Float16 As[64 * LDK];   // 17,408 B (aliased by f32 T in MODE 1)
    __shared__ alignas(16) _Float16 Bs[64 * LDK];
    __shared__ float rowacc[64];
    __shared__ float colacc[64];

    const int b = blockIdx.y;
    int it = 0, rem = blockIdx.x;                   // 0..54 -> (it, jt), it <= jt
    while (rem >= 10 - it) { rem -= 10 - it; ++it; }
    const int jt = it + rem;
    const bool diag = (it == jt);

    const int tid  = threadIdx.x;
    const int wave = tid >> 6;
    const int lane = tid & 63;
    const int l16  = lane & 15;
    const int quad = lane >> 4;
    const int rowhalf = wave >> 1;                  // 2x2 wave grid over the 64x64 tile
    const int colhalf = wave & 1;

    const float* xb = x + (size_t)b * DIM_ * MM;
    const float* db = d + b * DIM_;

    stage_tile(xb + (size_t)(it * 64) * MM, As, tid);
    if (!diag) stage_tile(xb + (size_t)(jt * 64) * MM, Bs, tid);
    if (MODE == 0) {
        if (tid < 64)       rowacc[tid] = 0.f;
        else if (tid < 128) colacc[tid - 64] = 0.f;
    }

    const float expt = expf(t[0]);
    const int rbase = it * 64 + rowhalf * 32;
    const int cbase = jt * 64 + colhalf * 32;

    float dr[2][4], rmr[2][4], rmc[2], tb = 0.f;
    #pragma unroll
    for (int ti = 0; ti < 2; ++ti)
        #pragma unroll
        for (int r = 0; r < 4; ++r) {
            const int gi = rbase + ti * 16 + quad * 4 + r;
            dr[ti][r] = db[gi];
            if (MODE == 1) rmr[ti][r] = rowsum[b * DIM_ + gi] * (1.0f / 640.0f);
        }
    const float dcv[2] = { db[cbase + l16], db[cbase + 16 + l16] };
    if (MODE == 1) {
        rmc[0] = rowsum[b * DIM_ + cbase + l16]      * (1.0f / 640.0f);
        rmc[1] = rowsum[b * DIM_ + cbase + 16 + l16] * (1.0f / 640.0f);
        tb = totsum[b] * (1.0f / (640.0f * 640.0f));
    }

    __syncthreads();

    const _Float16* Bp = diag ? As : Bs;
    f32x4 acc[2][2] = {};
    #pragma unroll
    for (int kk = 0; kk < 4; ++kk) {
        const int k = kk * 32 + quad * 8;
        half8 a0 = *(const half8*)(&As[(rowhalf * 32 + l16) * LDK + k]);
        half8 a1 = *(const half8*)(&As[(rowhalf * 32 + 16 + l16) * LDK + k]);
        half8 b0 = *(const half8*)(&Bp[(colhalf * 32 + l16) * LDK + k]);
        half8 b1 = *(const half8*)(&Bp[(colhalf * 32 + 16 + l16) * LDK + k]);
        acc[0][0] = __builtin_amdgcn_mfma_f32_16x16x32_f16(a0, b0, acc[0][0], 0, 0, 0);
        acc[0][1] = __builtin_amdgcn_mfma_f32_16x16x32_f16(a0, b1, acc[0][1], 0, 0, 0);
        acc[1][0] = __builtin_amdgcn_mfma_f32_16x16x32_f16(a1, b0, acc[1][0], 0, 0, 0);
        acc[1][1] = __builtin_amdgcn_mfma_f32_16x16x32_f16(a1, b1, acc[1][1], 0, 0, 0);
    }

    if (MODE == 0) {
        // ---- sums only
        float cp0 = 0.f, cp1 = 0.f;
        #pragma unroll
        for (int ti = 0; ti < 2; ++ti) {
            #pragma unroll
            for (int r = 0; r < 4; ++r) {
                const int gi = rbase + ti * 16 + quad * 4 + r;
                float v0, v1;
                {
                    const int gj = cbase + l16;
                    float raw = dr[ti][r] + dcv[0] - 2.0f * acc[ti][0][r];
                    raw = (gi == gj) ? 1e-4f : fmaxf(raw, 1e-4f);
                    v0 = sqrtf(expt * raw + 1e-5f);
                }
                {
                    const int gj = cbase + 16 + l16;
                    float raw = dr[ti][r] + dcv[1] - 2.0f * acc[ti][1][r];
                    raw = (gi == gj) ? 1e-4f : fmaxf(raw, 1e-4f);
                    v1 = sqrtf(expt * raw + 1e-5f);
                }
                cp0 += v0;
                cp1 += v1;
                float s = v0 + v1;
                s += __shfl_xor(s, 1, 64);
                s += __shfl_xor(s, 2, 64);
                s += __shfl_xor(s, 4, 64);
                s += __shfl_xor(s, 8, 64);
                if (l16 == 0)
                    atomicAdd(&rowacc[rowhalf * 32 + ti * 16 + quad * 4 + r], s);
            }
        }
        cp0 += __shfl_xor(cp0, 16, 64); cp0 += __shfl_xor(cp0, 32, 64);
        cp1 += __shfl_xor(cp1, 16, 64); cp1 += __shfl_xor(cp1, 32, 64);
        if (quad == 0) {
            atomicAdd(&colacc[colhalf * 32 + l16],      cp0);
            atomicAdd(&colacc[colhalf * 32 + 16 + l16], cp1);
        }
        __syncthreads();
        if (tid < 64) {     // wave 0: global row sums + batch total
            const float ra = rowacc[tid];
            const float ca = diag ? 0.f : colacc[tid];
            atomicAdd(&rowsum[b * DIM_ + it * 64 + tid], ra);
            if (!diag) atomicAdd(&rowsum[b * DIM_ + jt * 64 + tid], ca);
            float val = ra + ca;
            #pragma unroll
            for (int off = 32; off; off >>= 1) val += __shfl_down(val, off, 64);
            if (tid == 0) atomicAdd(&totsum[b], val);
        }
    } else {
        // ---- centered output, both triangles
        float* T = (float*)As;              // 64 x TSF f32 tile aliases As
        __syncthreads();                    // all MFMA frag reads done
        #pragma unroll
        for (int ti = 0; ti < 2; ++ti) {
            #pragma unroll
            for (int r = 0; r < 4; ++r) {
                const int gi = rbase + ti * 16 + quad * 4 + r;
                const int ri = rowhalf * 32 + ti * 16 + quad * 4 + r;
                #pragma unroll
                for (int tj = 0; tj < 2; ++tj) {
                    const int gj = cbase + tj * 16 + l16;
                    float raw = dr[ti][r] + dcv[tj] - 2.0f * acc[ti][tj][r];
                    raw = (gi == gj) ? 1e-4f : fmaxf(raw, 1e-4f);
                    const float v = sqrtf(expt * raw + 1e-5f);
                    T[ri * TSF + colhalf * 32 + tj * 16 + l16] =
                        v - rmr[ti][r] - rmc[tj] + tb;
                }
            }
        }
        __syncthreads();
        const size_t ob = (size_t)b * DIM_ * DIM_;
        #pragma unroll
        for (int w = tid; w < 1024; w += 256) {
            const int r2 = w >> 4;
            const int c2 = (w & 15) * 4;
            const float4 vv = *(const float4*)&T[r2 * TSF + c2];
            *(float4*)(out + ob + (size_t)(it * 64 + r2) * DIM_ + jt * 64 + c2) = vv;
            if (!diag) {
                float4 vt;
                vt.x = T[(c2 + 0) * TSF + r2];
                vt.y = T[(c2 + 1) * TSF + r2];
                vt.z = T[(c2 + 2) * TSF + r2];
                vt.w = T[(c2 + 3) * TSF + r2];
                *(float4*)(out + ob + (size_t)(jt * 64 + r2) * DIM_ + it * 64 + c2) = vt;
            }
        }
    }
}

// ---------------------------------------------------------------- launch
extern "C" void kernel_launch(void* const* d_in, const int* in_sizes, int n_in,
                              void* d_out, int out_size, void* d_ws, size_t ws_size,
                              hipStream_t stream) {
    const float* x = (const float*)d_in[0];
    const float* t = (const float*)d_in[1];
    float* out = (float*)d_out;

    char* ws = (char*)d_ws;
    float* d      = (float*)(ws);               // 327,680 B
    float* rowsum = (float*)(ws + 327680);      // 327,680 B
    float* totsum = (float*)(ws + 2 * 327680);  // 512 B

    prep_d<<<dim3((NB * DIM_) / 4), dim3(256), 0, stream>>>(x, d, rowsum, totsum);
    bdc_pass<0><<<dim3(55, NB), dim3(256), 0, stream>>>(x, d, t, rowsum, totsum, nullptr);
    bdc_pass<1><<<dim3(55, NB), dim3(256), 0, stream>>>(x, d, t, rowsum, totsum, out);
}